// Round 6
// baseline (129.238 us; speedup 1.0000x reference)
//
#include <hip/hip_runtime.h>

// out = x @ (Wc + Wn) + b   -- gamma/segment ops in the reference are dead code.
// x: [100000,128] f32, Wc/Wn: [128,128] f32, b: [128] f32, out: [100000,128] f32.
//
// R5 (resubmit; previous run died to container infra, not the kernel).
// NO-LDS gemm. The 32KB transposed weight table fits the per-CU L1
// exactly and is identical across all 782 blocks -> fragment reads straight
// from global are L1/L2-hot. This deletes: staging loads, ds_writes, the
// barrier (waves fully independent), all ds_reads, and the LDS occupancy cap.
// Keeps: cvt_pk bf16 casts, swapped-operand D[n][m] + dwordx4 epilogue,
// late bias load. Plain stores (R4's nontemporal confounded its regression).

#define NROWS 100000

typedef __attribute__((ext_vector_type(8))) __bf16 bf16x8;
typedef __attribute__((ext_vector_type(4))) float f32x4;

__device__ __forceinline__ bf16x8 pack8(const float4 lo, const float4 hi) {
    bf16x8 r;
    r[0] = (__bf16)lo.x; r[1] = (__bf16)lo.y; r[2] = (__bf16)lo.z; r[3] = (__bf16)lo.w;
    r[4] = (__bf16)hi.x; r[5] = (__bf16)hi.y; r[6] = (__bf16)hi.z; r[7] = (__bf16)hi.w;
    return r;
}

// Build Wt[n][k] = bf16(Wc[k][n] + Wn[k][n]) in workspace (transposed so the
// MFMA A-fragment read is 8 contiguous bf16 = one global_load_dwordx4).
__global__ void prep_wt(const float* __restrict__ Wc, const float* __restrict__ Wn,
                        unsigned short* __restrict__ wt) {
    int i = blockIdx.x * 256 + threadIdx.x;   // 16384 outputs, wt laid out [n][k]
    int n = i >> 7, k = i & 127;
    __bf16 v = (__bf16)(Wc[k * 128 + n] + Wn[k * 128 + n]);
    wt[i] = __builtin_bit_cast(unsigned short, v);
}

// 128 rows per block, 4 waves x 32 rows, full N=128 / K=128 per block.
__global__ __launch_bounds__(256) void gemm_bias(
    const float* __restrict__ x, const unsigned short* __restrict__ wt,
    const float* __restrict__ bias_g, float* __restrict__ out) {

    const int tid  = threadIdx.x;
    const int wave = tid >> 6;
    const int lane = tid & 63;
    const int quad = lane >> 4;
    const int l16  = lane & 15;

    const long rowbase = (long)blockIdx.x * 128 + wave * 32;
    if (rowbase >= NROWS) return;   // 100000 % 32 == 0: whole waves drop out

    // x fragments (MFMA B-operand): B[k = quad*8+j][m = lane&15]
    const float* xr0 = x + (rowbase + l16) * 128;
    const float* xr1 = xr0 + 16 * 128;

    f32x4 acc[2][8] = {};   // [m-subtile][n-tile]; D[n][m] layout (swapped ops)

    #pragma unroll
    for (int kc = 0; kc < 4; ++kc) {
        const int ko = kc * 32 + quad * 8;
        float4 a0lo = *(const float4*)(xr0 + ko);
        float4 a0hi = *(const float4*)(xr0 + ko + 4);
        float4 a1lo = *(const float4*)(xr1 + ko);
        float4 a1hi = *(const float4*)(xr1 + ko + 4);
        bf16x8 a0 = pack8(a0lo, a0hi);
        bf16x8 a1 = pack8(a1lo, a1hi);
        #pragma unroll
        for (int ct = 0; ct < 8; ++ct) {
            // Wt fragment (MFMA A-operand): A[n = lane&15][k = quad*8+j],
            // read straight from global -- L1-resident (32KB table, shared by
            // every block). 16B aligned (k multiple of 8).
            bf16x8 wf = *(const bf16x8*)&wt[(ct * 16 + l16) * 128 + ko];
            // D[i=n][j=m]: out[m][n] = sum_k x[m][k] * Wt[n][k]
            acc[0][ct] = __builtin_amdgcn_mfma_f32_16x16x32_bf16(wf, a0, acc[0][ct], 0, 0, 0);
            acc[1][ct] = __builtin_amdgcn_mfma_f32_16x16x32_bf16(wf, a1, acc[1][ct], 0, 0, 0);
        }
    }

    // Bias loaded late: epilogue-only live range.
    float4 bv[8];
    #pragma unroll
    for (int ct = 0; ct < 8; ++ct)
        bv[ct] = *(const float4*)(bias_g + ct * 16 + quad * 4);

    // C/D layout: col(j=m) = lane&15, row(i=n) = quad*4 + reg  [m89/m91]
    // => each lane's 4 regs are 4 consecutive output columns: dwordx4 stores,
    // each instruction covering full 64B lines (4 quads tile 64B per row).
    #pragma unroll
    for (int mt = 0; mt < 2; ++mt) {
        float* orow = out + (rowbase + mt * 16 + l16) * 128;
        #pragma unroll
        for (int ct = 0; ct < 8; ++ct) {
            float4 st4;
            st4.x = acc[mt][ct][0] + bv[ct].x;
            st4.y = acc[mt][ct][1] + bv[ct].y;
            st4.z = acc[mt][ct][2] + bv[ct].z;
            st4.w = acc[mt][ct][3] + bv[ct].w;
            *(float4*)(orow + ct * 16 + quad * 4) = st4;
        }
    }
}

extern "C" void kernel_launch(void* const* d_in, const int* in_sizes, int n_in,
                              void* d_out, int out_size, void* d_ws, size_t ws_size,
                              hipStream_t stream) {
    const float* x  = (const float*)d_in[0];
    // d_in[1] = edge_index (int64) -- dead code in the reference, never read.
    const float* Wc = (const float*)d_in[2];
    const float* Wn = (const float*)d_in[3];
    const float* b  = (const float*)d_in[4];
    unsigned short* wt = (unsigned short*)d_ws;   // 32 KB scratch
    float* out = (float*)d_out;

    prep_wt<<<64, 256, 0, stream>>>(Wc, Wn, wt);
    const int nblocks = (NROWS + 127) / 128;      // 782
    gemm_bias<<<nblocks, 256, 0, stream>>>(x, wt, b, out);
}

// Round 7
// 113.362 us; speedup vs baseline: 1.1400x; 1.1400x over previous
//
#include <hip/hip_runtime.h>

// out = x @ (Wc + Wn) + b   -- gamma/segment ops in the reference are dead code.
// x: [100000,128] f32, Wc/Wn: [128,128] f32, b: [128] f32, out: [100000,128] f32.
//
// R7: occupancy experiment. R5's counters showed the gemm is latency-bound
// (MfmaUtil 2.4%, VALUBusy 2.6%, occ 18.6%). Keep the proven LDS dataflow
// (R0/R3) but go 512 threads / 8 waves per 128-row block: 16 rows per wave,
// 3 resident blocks/CU = 24 waves/CU (75%) instead of 12 (37%). Per-wave
// state halves (acc 32 VGPRs). Same LDS (34.8KB), same grid (782), same
// barrier discipline (tail waves exit AFTER __syncthreads).

#define NROWS 100000

typedef __attribute__((ext_vector_type(8))) __bf16 bf16x8;
typedef __attribute__((ext_vector_type(8))) unsigned short u16x8;
typedef __attribute__((ext_vector_type(4))) float f32x4;

__device__ __forceinline__ bf16x8 pack8(const float4 lo, const float4 hi) {
    bf16x8 r;
    r[0] = (__bf16)lo.x; r[1] = (__bf16)lo.y; r[2] = (__bf16)lo.z; r[3] = (__bf16)lo.w;
    r[4] = (__bf16)hi.x; r[5] = (__bf16)hi.y; r[6] = (__bf16)hi.z; r[7] = (__bf16)hi.w;
    return r;
}

// Build Wt[n][k] = bf16(Wc[k][n] + Wn[k][n]) in workspace (transposed so the
// MFMA A-fragment read is 8 contiguous bf16 = one ds_read_b128).
__global__ void prep_wt(const float* __restrict__ Wc, const float* __restrict__ Wn,
                        unsigned short* __restrict__ wt) {
    int i = blockIdx.x * 256 + threadIdx.x;   // 16384 outputs, wt laid out [n][k]
    int n = i >> 7, k = i & 127;
    __bf16 v = (__bf16)(Wc[k * 128 + n] + Wn[k * 128 + n]);
    wt[i] = __builtin_bit_cast(unsigned short, v);
}

// 128 rows per block, 8 waves x 16 rows, full N=128 / K=128 per block.
__global__ __launch_bounds__(512) void gemm_bias(
    const float* __restrict__ x, const unsigned short* __restrict__ wt,
    const float* __restrict__ bias_g, float* __restrict__ out) {

    // 136-short row stride: 16B-aligned rows (272 = 17*16), benign aliasing
    // on the b128 fragment reads (SQ_LDS_BANK_CONFLICT measured 0).
    __shared__ __align__(16) unsigned short sWt[128 * 136];

    const int tid = threadIdx.x;
    // Stage Wt (32 KB) into LDS: 2048 x 16B chunks, coalesced global reads.
    #pragma unroll
    for (int it = 0; it < 4; ++it) {
        int idx8 = it * 512 + tid;           // chunk id, 16 chunks per row
        int n = idx8 >> 4;
        int k = (idx8 & 15) << 3;
        *(u16x8*)&sWt[n * 136 + k] = *(const u16x8*)(wt + (idx8 << 3));
    }
    __syncthreads();

    const int wave = tid >> 6;               // 0..7
    const int lane = tid & 63;
    const int quad = lane >> 4;
    const int l16  = lane & 15;

    const long rowbase = (long)blockIdx.x * 128 + wave * 16;
    if (rowbase >= NROWS) return;   // 100000 % 16 == 0: whole waves drop out
                                    // (after the barrier: no hang)

    // x fragments (MFMA B-operand): B[k = quad*8+j][m = lane&15]
    const float* xr = x + (rowbase + l16) * 128;

    f32x4 acc[8] = {};   // 8 n-tiles; D[n][m] layout (swapped operands)

    #pragma unroll
    for (int kc = 0; kc < 4; ++kc) {
        const int ko = kc * 32 + quad * 8;
        float4 alo = *(const float4*)(xr + ko);
        float4 ahi = *(const float4*)(xr + ko + 4);
        bf16x8 a = pack8(alo, ahi);
        #pragma unroll
        for (int ct = 0; ct < 8; ++ct) {
            // Wt fragment (MFMA A-operand): A[n = lane&15][k = quad*8+j]
            bf16x8 wf = *(const bf16x8*)&sWt[(ct * 16 + l16) * 136 + ko];
            // D[i=n][j=m]: out[m][n] = sum_k x[m][k] * Wt[n][k]
            acc[ct] = __builtin_amdgcn_mfma_f32_16x16x32_bf16(wf, a, acc[ct], 0, 0, 0);
        }
    }

    // Bias loaded late: epilogue-only live range.
    float4 bv[8];
    #pragma unroll
    for (int ct = 0; ct < 8; ++ct)
        bv[ct] = *(const float4*)(bias_g + ct * 16 + quad * 4);

    // C/D layout: col(j=m) = lane&15, row(i=n) = quad*4 + reg  [m89/m91]
    // => each lane's 4 regs are 4 consecutive output columns: dwordx4 stores;
    // the 4 quads tile each 64B half-line, 16 rows per instruction.
    float* orow = out + (rowbase + l16) * 128;
    #pragma unroll
    for (int ct = 0; ct < 8; ++ct) {
        float4 st4;
        st4.x = acc[ct][0] + bv[ct].x;
        st4.y = acc[ct][1] + bv[ct].y;
        st4.z = acc[ct][2] + bv[ct].z;
        st4.w = acc[ct][3] + bv[ct].w;
        *(float4*)(orow + ct * 16 + quad * 4) = st4;
    }
}

extern "C" void kernel_launch(void* const* d_in, const int* in_sizes, int n_in,
                              void* d_out, int out_size, void* d_ws, size_t ws_size,
                              hipStream_t stream) {
    const float* x  = (const float*)d_in[0];
    // d_in[1] = edge_index (int64) -- dead code in the reference, never read.
    const float* Wc = (const float*)d_in[2];
    const float* Wn = (const float*)d_in[3];
    const float* b  = (const float*)d_in[4];
    unsigned short* wt = (unsigned short*)d_ws;   // 32 KB scratch
    float* out = (float*)d_out;

    prep_wt<<<64, 256, 0, stream>>>(Wc, Wn, wt);
    const int nblocks = (NROWS + 127) / 128;      // 782
    gemm_bias<<<nblocks, 512, 0, stream>>>(x, wt, b, out);
}